// Round 14
// baseline (384.404 us; speedup 1.0000x reference)
//
#include <hip/hip_runtime.h>
#include <math.h>

typedef __attribute__((ext_vector_type(8))) short short8;
typedef __attribute__((ext_vector_type(4))) float f32x4;

#define Bn   4096
#define Dn   768
#define Cn   80
#define H1   256
#define H2   64
#define H3   16
#define H4   4

// fp32 -> bf16 RTNE
__device__ inline ushort f2bf(float f) {
    union { float f; unsigned u; } v; v.f = f;
    unsigned r = v.u + 0x7fffu + ((v.u >> 16) & 1u);
    return (ushort)(r >> 16);
}
__device__ inline unsigned pack2(float a, float b) {
    return (unsigned)f2bf(a) | ((unsigned)f2bf(b) << 16);
}
__device__ inline void load_lds16(const void* g, void* l) {
    __builtin_amdgcn_global_load_lds(
        (const __attribute__((address_space(1))) void*)g,
        (__attribute__((address_space(3))) void*)l, 16, 0, 0);
}

#define FENCE() asm volatile("" ::: "memory")
#define BAR() do { FENCE(); __builtin_amdgcn_sched_barrier(0); \
                   __builtin_amdgcn_s_barrier(); \
                   __builtin_amdgcn_sched_barrier(0); FENCE(); } while (0)
#define VMCNT12() do { asm volatile("s_waitcnt vmcnt(12)" ::: "memory"); \
                       __builtin_amdgcn_sched_barrier(0); } while (0)
#define VMCNT0() do { asm volatile("s_waitcnt vmcnt(0)" ::: "memory"); \
                      __builtin_amdgcn_sched_barrier(0); } while (0)

// ===================== Pass A: merged conversion kernel (unchanged from R11) =====================
__global__ __launch_bounds__(256)
void convert_all(const float* __restrict__ hidden, ushort* __restrict__ hbs,
                 const float* __restrict__ W1, const float* __restrict__ rW1,
                 ushort* __restrict__ dstW1,
                 const float* __restrict__ W2, const float* __restrict__ rW2,
                 const float* __restrict__ W3, const float* __restrict__ rW3,
                 ushort* __restrict__ dstW2, ushort* __restrict__ dstW3)
{
    __shared__ float l[32 * H1];         // 32KB
    const int t = threadIdx.x;
    const int b = blockIdx.x;

    if (b < 768) {
        const int kt = b % 24;
        const int bt = b / 24;
        char* out = (char*)hbs + ((size_t)bt * 24 + kt) * 8192;
        #pragma unroll
        for (int ch = 0; ch < 2; ++ch) {
            const int o = (ch * 256 + t) * 16;
            const int r = o >> 6;
            const int s = (o >> 4) & 3;
            const int k0 = (s ^ ((r >> 1) & 3)) * 8;
            const float* src = hidden + (size_t)(bt * 128 + r) * Dn + kt * 32 + k0;
            const float4 f0 = ((const float4*)src)[0];
            const float4 f1 = ((const float4*)src)[1];
            uint4 w;
            w.x = pack2(f0.x, f0.y); w.y = pack2(f0.z, f0.w);
            w.z = pack2(f1.x, f1.y); w.w = pack2(f1.z, f1.w);
            *(uint4*)(out + o) = w;
        }
    } else if (b < 4608) {
        const int i = b - 768;
        const int kt2 = i % 24;
        const int c   = (i / 24) % Cn;
        const int set = i / (24 * Cn);
        const float* src = (set ? rW1 : W1) + ((size_t)c * Dn + kt2 * 32) * H1;
        #pragma unroll
        for (int q = 0; q < 8; ++q)
            ((float4*)l)[q * 256 + t] = ((const float4*)src)[q * 256 + t];
        __syncthreads();
        char* out = (char*)dstW1 + (((size_t)set * Cn + c) * 24 + kt2) * 16384;
        #pragma unroll
        for (int rd = 0; rd < 4; ++rd) {
            const int o = (rd * 256 + t) * 16;
            const int n = o >> 6;
            const int s = (o >> 4) & 3;
            const int kk0 = (s ^ ((n >> 1) & 3)) * 8;
            uint4 w;
            w.x = pack2(l[(kk0 + 0) * H1 + n], l[(kk0 + 1) * H1 + n]);
            w.y = pack2(l[(kk0 + 2) * H1 + n], l[(kk0 + 3) * H1 + n]);
            w.z = pack2(l[(kk0 + 4) * H1 + n], l[(kk0 + 5) * H1 + n]);
            w.w = pack2(l[(kk0 + 6) * H1 + n], l[(kk0 + 7) * H1 + n]);
            *(uint4*)(out + o) = w;
        }
    } else {
        const int i = b - 4608;
        const int bx  = i % 5;
        const int c   = (i / 5) % Cn;
        const int set = i / (5 * Cn);
        if (bx < 4) {
            const float* src = (set ? rW2 : W2) + ((size_t)c * H1 + bx * 64) * H2;
            #pragma unroll
            for (int q = 0; q < 4; ++q)
                ((float4*)l)[q * 256 + t] = ((const float4*)src)[q * 256 + t];
            __syncthreads();
            char* out = (char*)dstW2 + (((size_t)set * Cn + c) * 4 + bx) * 8192;
            #pragma unroll
            for (int rd = 0; rd < 2; ++rd) {
                const int idx = rd * 256 + t;
                const int n = idx >> 3;
                const int s = idx & 7;
                const int o = n * 128 + ((s << 4) ^ ((n & 7) << 4));
                const int kk0 = s * 8;
                uint4 w;
                w.x = pack2(l[(kk0 + 0) * H2 + n], l[(kk0 + 1) * H2 + n]);
                w.y = pack2(l[(kk0 + 2) * H2 + n], l[(kk0 + 3) * H2 + n]);
                w.z = pack2(l[(kk0 + 4) * H2 + n], l[(kk0 + 5) * H2 + n]);
                w.w = pack2(l[(kk0 + 6) * H2 + n], l[(kk0 + 7) * H2 + n]);
                *(uint4*)(out + o) = w;
            }
        } else if (t < 128) {
            const float* src = (set ? rW3 : W3) + (size_t)c * (H2 * H3);
            char* out = (char*)dstW3 + ((size_t)set * Cn + c) * 2048;
            const int o = t * 16;
            const int n = o >> 7;
            const int slot = (o >> 4) & 7;
            const int kk0 = (slot ^ (n & 7)) * 8;
            uint4 w;
            w.x = pack2(src[(kk0 + 0) * H3 + n], src[(kk0 + 1) * H3 + n]);
            w.y = pack2(src[(kk0 + 2) * H3 + n], src[(kk0 + 3) * H3 + n]);
            w.z = pack2(src[(kk0 + 4) * H3 + n], src[(kk0 + 5) * H3 + n]);
            w.w = pack2(src[(kk0 + 6) * H3 + n], src[(kk0 + 7) * H3 + n]);
            *(uint4*)(out + o) = w;
        }
    }
}

// ===================== Pass B: 128x256 block, 2 waves of 128x128, BK=32, ring-3 =====================
// LDS (72KB): A ring 3 x 8KB @ 0; B ring 3 x 16KB @ 24576.
// Post-loop reuse: x1 bf16 [128 rows][512B] @0 (64KB); then x2 bf16 [128][128B] @0.
// 1 wave/SIMD (big-acc trade: measured phases are ADDITIVE, so TLP provided zero
// overlap; 128x128 wave tile cuts LDS traffic/FLOP by 33% using the idle VGPRs).
// Swapped-operand MFMAs: lane&15 = batch row, (lane>>4)*4+r = feature.
// Ledger (R11 scaled): iter j = {16 frag reads | stage(j+2): 12 issues | VMCNT12 | 64 MFMA} BAR.

__device__ __forceinline__ void stageA(char* lds, const char* hb, int slot, int kt, int t) {
    const char* g = hb + (size_t)kt * 8192 + t * 16;
    char* l = lds + slot * 8192 + t * 16;
    #pragma unroll
    for (int i = 0; i < 4; ++i)
        load_lds16(g + i * 2048, l + i * 2048);
}
__device__ __forceinline__ void stageB(char* lds, const char* w1b, int slot, int kt, int t) {
    const char* g = w1b + (size_t)kt * 16384 + t * 16;
    char* l = lds + 24576 + slot * 16384 + t * 16;
    #pragma unroll
    for (int i = 0; i < 8; ++i)
        load_lds16(g + i * 2048, l + i * 2048);
}

__global__ __launch_bounds__(128, 1)
void scores_mfma_w128(const ushort* __restrict__ hbs, const ushort* __restrict__ W1ts,
                      const ushort* __restrict__ W2ts, const ushort* __restrict__ W3ts,
                      const float* __restrict__ b1, const float* __restrict__ rb1,
                      const float* __restrict__ b2, const float* __restrict__ rb2,
                      const float* __restrict__ b3, const float* __restrict__ rb3,
                      const float* __restrict__ W4, const float* __restrict__ rW4,
                      const float* __restrict__ b4, const float* __restrict__ rb4,
                      const float* __restrict__ W5, const float* __restrict__ rW5,
                      const float* __restrict__ b5, const float* __restrict__ rb5,
                      float* __restrict__ scores)
{
    __shared__ uint4 smv[73728 / 16];    // 72KB
    char* lds = (char*)smv;

    const int t = threadIdx.x;
    const int wid = t >> 6, lane = t & 63;   // wid 0..1 = column half
    const int lrow = lane & 15;
    const int lkg  = lane >> 4;          // 0..3
    const int lk   = lkg * 8;
    const int wcn = wid;                 // col half owned by this wave

    // bijective XCD swizzle, nwg = 5120
    const int cpx = 5120 >> 3;
    const int wg  = (blockIdx.x & 7) * cpx + (blockIdx.x >> 3);
    const int set = wg / 2560;
    const int rem = wg % 2560;
    const int c   = rem / 32;
    const int bt  = rem % 32;            // 128-row tile index

    const float* pb1 = set ? rb1 : b1;
    const float* pb2 = set ? rb2 : b2;
    const float* pb3 = set ? rb3 : b3;
    const float* pW4 = set ? rW4 : W4;  const float* pb4 = set ? rb4 : b4;
    const float* pW5 = set ? rW5 : W5;  const float* pb5 = set ? rb5 : b5;

    const char* hb  = (const char*)hbs + (size_t)bt * 196608;               // 24*8KB
    const char* w1b = (const char*)W1ts + (size_t)(set * Cn + c) * 393216;  // 24*16KB

    f32x4 acc[8][8];
    #pragma unroll
    for (int i = 0; i < 8; ++i)
        #pragma unroll
        for (int j = 0; j < 8; ++j)
            acc[i][j] = (f32x4){0.f, 0.f, 0.f, 0.f};

    // -------- prologue: tiles 0,1 (24 issues); wait tile 0 (leave tile 1's 12)
    stageA(lds, hb, 0, 0, t);  stageB(lds, w1b, 0, 0, t);
    stageA(lds, hb, 1, 1, t);  stageB(lds, w1b, 1, 1, t);
    VMCNT12();
    BAR();

    // -------- K loop: 24 iters of K=32, ONE barrier per iter
    #pragma unroll 3
    for (int j = 0; j < 24; ++j) {
        const int rs = j % 3;
        short8 breg[8], areg[8];
        {
            const char* bb = lds + 24576 + rs * 16384;
            const char* ab = lds + rs * 8192;
            #pragma unroll
            for (int nt = 0; nt < 8; ++nt) {
                const int col = wcn * 128 + nt * 16 + lrow;
                breg[nt] = *(const short8*)(bb + col * 64
                              + ((2 * lk) ^ (((col >> 1) & 3) << 4)));
            }
            #pragma unroll
            for (int mt = 0; mt < 8; ++mt) {
                const int row = mt * 16 + lrow;
                areg[mt] = *(const short8*)(ab + row * 64
                              + ((2 * lk) ^ (((row >> 1) & 3) << 4)));
            }
        }
        {
            const int ws = (j + 2) % 3;
            int ka = j + 2; if (ka >= 24) ka -= 24;   // tail wrap: dead but uniform
            stageA(lds, hb, ws, ka, t);
            stageB(lds, w1b, ws, ka, t);
        }
        VMCNT12();
        __builtin_amdgcn_s_setprio(1);
        #pragma unroll
        for (int mt = 0; mt < 8; ++mt)
            #pragma unroll
            for (int nt = 0; nt < 8; ++nt)
                acc[mt][nt] = __builtin_amdgcn_mfma_f32_16x16x32_bf16(
                    breg[nt], areg[mt], acc[mt][nt], 0, 0, 0);
        __builtin_amdgcn_s_setprio(0);
        BAR();
    }
    VMCNT0();    // drain wrapped dead stages before LDS reuse
    BAR();

    // -------- epilogue 1: bias + relu -> x1 bf16 [128 rows][256 feat] swizzled
    {
        float4 bias1[8];
        #pragma unroll
        for (int nt = 0; nt < 8; ++nt)
            bias1[nt] = *(const float4*)&pb1[(size_t)c * H1 + wcn * 128 + nt * 16 + lkg * 4];
        #pragma unroll
        for (int mt = 0; mt < 8; ++mt) {
            const int row = mt * 16 + lrow;
            const int swz = (row & 7) << 4;
            #pragma unroll
            for (int nt = 0; nt < 8; ++nt) {
                const float* bb = (const float*)&bias1[nt];
                uint2 w;
                w.x = pack2(fmaxf(acc[mt][nt][0] + bb[0], 0.f),
                            fmaxf(acc[mt][nt][1] + bb[1], 0.f));
                w.y = pack2(fmaxf(acc[mt][nt][2] + bb[2], 0.f),
                            fmaxf(acc[mt][nt][3] + bb[3], 0.f));
                const int off = row * 512 + ((wcn * 256 + nt * 32 + lkg * 8) ^ swz);
                *(uint2*)(lds + off) = w;
            }
        }
    }
    BAR();

    // -------- layer 2: M=128 N=64 K=256; per wave 64 rows (m2 0..3)
    f32x4 acc2[4][4];
    #pragma unroll
    for (int i = 0; i < 4; ++i)
        #pragma unroll
        for (int j = 0; j < 4; ++j)
            acc2[i][j] = (f32x4){0.f, 0.f, 0.f, 0.f};
    {
        const char* w2b = (const char*)W2ts + (size_t)(set * Cn + c) * 32768;
        #pragma unroll
        for (int ksz = 0; ksz < 8; ++ksz) {
            short8 b2r[4], a2[4];
            const int kk2 = (ksz & 1) * 32 + lk;
            #pragma unroll
            for (int nt = 0; nt < 4; ++nt) {
                const int col = nt * 16 + lrow;
                b2r[nt] = *(const short8*)(w2b + (ksz >> 1) * 8192
                             + ((col * 128 + 2 * kk2) ^ ((col & 7) << 4)));
            }
            const int k = ksz * 32 + lk;
            #pragma unroll
            for (int m2 = 0; m2 < 4; ++m2) {
                const int row = wid * 64 + m2 * 16 + lrow;
                a2[m2] = *(const short8*)(lds + ((row * 512 + 2 * k) ^ ((row & 7) << 4)));
            }
            #pragma unroll
            for (int m2 = 0; m2 < 4; ++m2)
                #pragma unroll
                for (int nt = 0; nt < 4; ++nt)
                    acc2[m2][nt] = __builtin_amdgcn_mfma_f32_16x16x32_bf16(
                        b2r[nt], a2[m2], acc2[m2][nt], 0, 0, 0);
        }
    }
    BAR();

    // -------- epilogue 2: bias + relu -> x2 bf16 [128 rows][64 feat] swizzled (16KB @0)
    {
        float4 bias2[4];
        #pragma unroll
        for (int nt = 0; nt < 4; ++nt)
            bias2[nt] = *(const float4*)&pb2[(size_t)c * H2 + nt * 16 + lkg * 4];
        #pragma unroll
        for (int m2 = 0; m2 < 4; ++m2) {
            const int row = wid * 64 + m2 * 16 + lrow;
            const int swz = (row & 7) << 4;
            #pragma unroll
            for (int nt = 0; nt < 4; ++nt) {
                const float* bb = (const float*)&bias2[nt];
                uint2 w;
                w.x = pack2(fmaxf(acc2[m2][nt][0] + bb[0], 0.f),
                            fmaxf(acc2[m2][nt][1] + bb[1], 0.f));
                w.y = pack2(fmaxf(acc2[m2][nt][2] + bb[2], 0.f),
                            fmaxf(acc2[m2][nt][3] + bb[3], 0.f));
                const int off = row * 128 + ((nt * 32 + lkg * 8) ^ swz);
                *(uint2*)(lds + off) = w;
            }
        }
    }
    BAR();

    // -------- layer 3 (MFMA) + layers 4-5 in-register; per wave 64 rows
    {
        const char* w3t = (const char*)W3ts + (size_t)(set * Cn + c) * 2048;
        short8 w3f[2];
        #pragma unroll
        for (int ks = 0; ks < 2; ++ks)
            w3f[ks] = *(const short8*)(w3t + lrow * 128
                         + ((2 * (ks * 32 + lk)) ^ ((lrow & 7) << 4)));
        f32x4 acc3[4];
        #pragma unroll
        for (int m2 = 0; m2 < 4; ++m2) acc3[m2] = (f32x4){0.f, 0.f, 0.f, 0.f};
        #pragma unroll
        for (int m2 = 0; m2 < 4; ++m2) {
            const int row = wid * 64 + m2 * 16 + lrow;
            #pragma unroll
            for (int ks = 0; ks < 2; ++ks) {
                const short8 xf = *(const short8*)(lds + row * 128
                                     + ((2 * (ks * 32 + lk)) ^ ((row & 7) << 4)));
                acc3[m2] = __builtin_amdgcn_mfma_f32_16x16x32_bf16(
                    w3f[ks], xf, acc3[m2], 0, 0, 0);
            }
        }

        const float4 b3v = *(const float4*)&pb3[(size_t)c * H3 + lkg * 4];
        const float* w4c = pW4 + (size_t)c * (H3 * H4);
        float4 w4r[4];
        #pragma unroll
        for (int r = 0; r < 4; ++r)
            w4r[r] = *(const float4*)&w4c[(lkg * 4 + r) * H4];
        const float4 b4v = *(const float4*)&pb4[(size_t)c * H4];
        const float4 w5v = *(const float4*)&pW5[(size_t)c * H4];
        const float bb5 = pb5[c];

        #pragma unroll
        for (int m2 = 0; m2 < 4; ++m2) {
            float p4[4] = {0.f, 0.f, 0.f, 0.f};
            #pragma unroll
            for (int r = 0; r < 4; ++r) {
                const float x3 = fmaxf(acc3[m2][r] + ((const float*)&b3v)[r], 0.f);
                const float* wr4 = (const float*)&w4r[r];
                #pragma unroll
                for (int o = 0; o < 4; ++o)
                    p4[o] = fmaf(x3, wr4[o], p4[o]);
            }
            #pragma unroll
            for (int o = 0; o < 4; ++o) {
                p4[o] += __shfl_xor(p4[o], 16, 64);
                p4[o] += __shfl_xor(p4[o], 32, 64);
            }
            float x5 = bb5;
            #pragma unroll
            for (int o = 0; o < 4; ++o)
                x5 = fmaf(fmaxf(p4[o] + ((const float*)&b4v)[o], 0.f),
                          ((const float*)&w5v)[o], x5);
            const float sc = 1.f / (1.f + expf(-x5));
            if (lkg == 0)
                scores[((size_t)set * Bn + bt * 128 + wid * 64 + m2 * 16 + lrow) * Cn + c] = sc;
        }
    }
}

// ===================== loss kernels =====================
__device__ inline float bce_f(float p, float y) {
    p = fminf(fmaxf(p, 1e-8f), 1.0f - 1e-8f);
    return -(y * logf(p) + (1.f - y) * log1pf(-p));
}

__global__ __launch_bounds__(128)
void loss_kernel(const float* __restrict__ scores, const int* __restrict__ labels,
                 float* __restrict__ pair_sum, float* __restrict__ np_sum,
                 int* __restrict__ pair_cnt)
{
    __shared__ float ss[Cn], lt[Cn];
    __shared__ int lab[Cn];
    __shared__ float redf[128], redn[128];
    __shared__ int redi[128];

    const int b = blockIdx.x, t = threadIdx.x;
    float np_local = 0.f, ps_local = 0.f;
    int pc_local = 0;

    if (t < Cn) {
        const float s  = scores[(size_t)b * Cn + t];
        const float sr = scores[(size_t)Bn * Cn + (size_t)b * Cn + t];
        const int l = labels[(size_t)b * Cn + t];
        ss[t] = s; lab[t] = l;
        lt[t] = logf(s / (sr + 1e-8f) + 1e-8f);
        if (t >= 20) {
            const float y = (float)l;
            np_local = fmaxf(bce_f(s, y) - bce_f(sr, y) - 0.1f, 0.f);
        }
    }
    __syncthreads();
    if (t < Cn && lab[t] == 0) {
        const float sj = ss[t], ltj = lt[t];
        #pragma unroll
        for (int i = 0; i < 20; ++i) {
            if (lab[i] == 1 && sj >= ss[i]) {
                const float z = -(lt[i] - ltj);
                ps_local += fmaxf(z, 0.f) + log1pf(expf(-fabsf(z)));
                pc_local++;
            }
        }
    }
    redf[t] = ps_local; redn[t] = np_local; redi[t] = pc_local;
    __syncthreads();
    for (int s = 64; s > 0; s >>= 1) {
        if (t < s) { redf[t] += redf[t + s]; redn[t] += redn[t + s]; redi[t] += redi[t + s]; }
        __syncthreads();
    }
    if (t == 0) { pair_sum[b] = redf[0]; np_sum[b] = redn[0]; pair_cnt[b] = redi[0]; }
}

__global__ __launch_bounds__(1024)
void final_kernel(const float* __restrict__ pair_sum, const int* __restrict__ pair_cnt,
                  const float* __restrict__ np_sum, float* __restrict__ out)
{
    __shared__ float r1[1024], r2[1024];
    __shared__ int ri[1024];
    const int t = threadIdx.x;
    float s1 = 0.f, s2 = 0.f; int c1 = 0;
    for (int i = t; i < Bn; i += 1024) { s1 += pair_sum[i]; c1 += pair_cnt[i]; s2 += np_sum[i]; }
    r1[t] = s1; r2[t] = s2; ri[t] = c1;
    __syncthreads();
    for (int s = 512; s > 0; s >>= 1) {
        if (t < s) { r1[t] += r1[t + s]; r2[t] += r2[t + s]; ri[t] += ri[t + s]; }
        __syncthreads();
    }
    if (t == 0) {
        const int n = ri[0];
        out[0] = (n > 0) ? (r1[0] / (float)(n > 1 ? n : 1)) : 0.f;
        out[1] = r2[0] / (float)(Bn * 60);
    }
}

// ===================== launch =====================
static inline size_t alup(size_t x) { return (x + 4095) & ~(size_t)4095; }

extern "C" void kernel_launch(void* const* d_in, const int* in_sizes, int n_in,
                              void* d_out, int out_size, void* d_ws, size_t ws_size,
                              hipStream_t stream)
{
    const float* hidden = (const float*)d_in[0];
    const int*   labels = (const int*)d_in[1];
    const float* W1 = (const float*)d_in[2];   const float* b1 = (const float*)d_in[3];
    const float* W2 = (const float*)d_in[4];   const float* b2 = (const float*)d_in[5];
    const float* W3 = (const float*)d_in[6];   const float* b3 = (const float*)d_in[7];
    const float* W4 = (const float*)d_in[8];   const float* b4 = (const float*)d_in[9];
    const float* W5 = (const float*)d_in[10];  const float* b5 = (const float*)d_in[11];
    const float* rW1 = (const float*)d_in[12]; const float* rb1 = (const float*)d_in[13];
    const float* rW2 = (const float*)d_in[14]; const float* rb2 = (const float*)d_in[15];
    const float* rW3 = (const float*)d_in[16]; const float* rb3 = (const float*)d_in[17];
    const float* rW4 = (const float*)d_in[18]; const float* rb4 = (const float*)d_in[19];
    const float* rW5 = (const float*)d_in[20]; const float* rb5 = (const float*)d_in[21];

    char* ws = (char*)d_ws;
    const size_t off_scores = 0;
    const size_t sz_scores  = (size_t)2 * Bn * Cn * 4;
    const size_t off_pair   = alup(off_scores + sz_scores);
    const size_t sz_pair    = (size_t)3 * Bn * 4;
    const size_t off_hbs    = alup(off_pair + sz_pair);
    const size_t sz_hbs     = (size_t)Bn * Dn * 2;
    const size_t off_w1t    = alup(off_hbs + sz_hbs);
    const size_t sz_w1t     = (size_t)2 * Cn * 24 * 16384;
    const size_t off_w2t    = alup(off_w1t + sz_w1t);
    const size_t sz_w2t     = (size_t)2 * Cn * 4 * 8192;
    const size_t off_w3t    = alup(off_w2t + sz_w2t);

    float* scoresb  = (float*)(ws + off_scores);
    float* pair_sum = (float*)(ws + off_pair);
    float* np_sum   = pair_sum + Bn;
    int*   pair_cnt = (int*)(np_sum + Bn);
    float* out      = (float*)d_out;

    ushort* hbs  = (ushort*)(ws + off_hbs);
    ushort* W1ts = (ushort*)(ws + off_w1t);
    ushort* W2ts = (ushort*)(ws + off_w2t);
    ushort* W3ts = (ushort*)(ws + off_w3t);

    convert_all<<<5408, 256, 0, stream>>>(hidden, hbs, W1, rW1, W1ts,
                                          W2, rW2, W3, rW3, W2ts, W3ts);

    scores_mfma_w128<<<5120, 128, 0, stream>>>(hbs, W1ts, W2ts, W3ts,
        b1, rb1, b2, rb2, b3, rb3, W4, rW4, b4, rb4, W5, rW5, b5, rb5,
        scoresb);
    loss_kernel<<<Bn, 128, 0, stream>>>(scoresb, labels, pair_sum, np_sum, pair_cnt);
    final_kernel<<<1, 1024, 0, stream>>>(pair_sum, pair_cnt, np_sum, out);
}

// Round 15
// 334.431 us; speedup vs baseline: 1.1494x; 1.1494x over previous
//
#include <hip/hip_runtime.h>
#include <math.h>

typedef __attribute__((ext_vector_type(8))) short short8;
typedef __attribute__((ext_vector_type(4))) float f32x4;

#define Bn   4096
#define Dn   768
#define Cn   80
#define H1   256
#define H2   64
#define H3   16
#define H4   4

// fp32 -> bf16 RTNE
__device__ inline ushort f2bf(float f) {
    union { float f; unsigned u; } v; v.f = f;
    unsigned r = v.u + 0x7fffu + ((v.u >> 16) & 1u);
    return (ushort)(r >> 16);
}
__device__ inline unsigned pack2(float a, float b) {
    return (unsigned)f2bf(a) | ((unsigned)f2bf(b) << 16);
}
__device__ inline void load_lds16(const void* g, void* l) {
    __builtin_amdgcn_global_load_lds(
        (const __attribute__((address_space(1))) void*)g,
        (__attribute__((address_space(3))) void*)l, 16, 0, 0);
}

#define FENCE() asm volatile("" ::: "memory")
#define BAR() do { FENCE(); __builtin_amdgcn_sched_barrier(0); \
                   __builtin_amdgcn_s_barrier(); \
                   __builtin_amdgcn_sched_barrier(0); FENCE(); } while (0)
#define VMCNT6() do { asm volatile("s_waitcnt vmcnt(6)" ::: "memory"); \
                      __builtin_amdgcn_sched_barrier(0); } while (0)
#define VMCNT0() do { asm volatile("s_waitcnt vmcnt(0)" ::: "memory"); \
                      __builtin_amdgcn_sched_barrier(0); } while (0)

// ===================== Pass A: merged conversion kernel =====================
// range [0,768):      hidden -> hbs: per (bt128,kt32) 8KB tile,
//                     element (r,k) at byte r*64 + ((2k) ^ (((r>>1)&3)<<4))
// range [768,4608):   W1 -> [set][c][kt] 256n x 32k tiles, byte n*64 + (2kk ^ (((n>>1)&3)<<4))
// range [4608,5408):  W2 (bx<4) 64n x 64k tiles (byte (n*128+2k)^((n&7)<<4)); bx==4: W3 tile
__global__ __launch_bounds__(256)
void convert_all(const float* __restrict__ hidden, ushort* __restrict__ hbs,
                 const float* __restrict__ W1, const float* __restrict__ rW1,
                 ushort* __restrict__ dstW1,
                 const float* __restrict__ W2, const float* __restrict__ rW2,
                 const float* __restrict__ W3, const float* __restrict__ rW3,
                 ushort* __restrict__ dstW2, ushort* __restrict__ dstW3)
{
    __shared__ float l[32 * H1];         // 32KB
    const int t = threadIdx.x;
    const int b = blockIdx.x;

    if (b < 768) {
        const int kt = b % 24;
        const int bt = b / 24;
        char* out = (char*)hbs + ((size_t)bt * 24 + kt) * 8192;
        #pragma unroll
        for (int ch = 0; ch < 2; ++ch) {
            const int o = (ch * 256 + t) * 16;
            const int r = o >> 6;
            const int s = (o >> 4) & 3;
            const int k0 = (s ^ ((r >> 1) & 3)) * 8;
            const float* src = hidden + (size_t)(bt * 128 + r) * Dn + kt * 32 + k0;
            const float4 f0 = ((const float4*)src)[0];
            const float4 f1 = ((const float4*)src)[1];
            uint4 w;
            w.x = pack2(f0.x, f0.y); w.y = pack2(f0.z, f0.w);
            w.z = pack2(f1.x, f1.y); w.w = pack2(f1.z, f1.w);
            *(uint4*)(out + o) = w;
        }
    } else if (b < 4608) {
        const int i = b - 768;
        const int kt2 = i % 24;
        const int c   = (i / 24) % Cn;
        const int set = i / (24 * Cn);
        const float* src = (set ? rW1 : W1) + ((size_t)c * Dn + kt2 * 32) * H1;
        #pragma unroll
        for (int q = 0; q < 8; ++q)
            ((float4*)l)[q * 256 + t] = ((const float4*)src)[q * 256 + t];
        __syncthreads();
        char* out = (char*)dstW1 + (((size_t)set * Cn + c) * 24 + kt2) * 16384;
        #pragma unroll
        for (int rd = 0; rd < 4; ++rd) {
            const int o = (rd * 256 + t) * 16;
            const int n = o >> 6;
            const int s = (o >> 4) & 3;
            const int kk0 = (s ^ ((n >> 1) & 3)) * 8;
            uint4 w;
            w.x = pack2(l[(kk0 + 0) * H1 + n], l[(kk0 + 1) * H1 + n]);
            w.y = pack2(l[(kk0 + 2) * H1 + n], l[(kk0 + 3) * H1 + n]);
            w.z = pack2(l[(kk0 + 4) * H1 + n], l[(kk0 + 5) * H1 + n]);
            w.w = pack2(l[(kk0 + 6) * H1 + n], l[(kk0 + 7) * H1 + n]);
            *(uint4*)(out + o) = w;
        }
    } else {
        const int i = b - 4608;
        const int bx  = i % 5;
        const int c   = (i / 5) % Cn;
        const int set = i / (5 * Cn);
        if (bx < 4) {
            const float* src = (set ? rW2 : W2) + ((size_t)c * H1 + bx * 64) * H2;
            #pragma unroll
            for (int q = 0; q < 4; ++q)
                ((float4*)l)[q * 256 + t] = ((const float4*)src)[q * 256 + t];
            __syncthreads();
            char* out = (char*)dstW2 + (((size_t)set * Cn + c) * 4 + bx) * 8192;
            #pragma unroll
            for (int rd = 0; rd < 2; ++rd) {
                const int idx = rd * 256 + t;
                const int n = idx >> 3;
                const int s = idx & 7;
                const int o = n * 128 + ((s << 4) ^ ((n & 7) << 4));
                const int kk0 = s * 8;
                uint4 w;
                w.x = pack2(l[(kk0 + 0) * H2 + n], l[(kk0 + 1) * H2 + n]);
                w.y = pack2(l[(kk0 + 2) * H2 + n], l[(kk0 + 3) * H2 + n]);
                w.z = pack2(l[(kk0 + 4) * H2 + n], l[(kk0 + 5) * H2 + n]);
                w.w = pack2(l[(kk0 + 6) * H2 + n], l[(kk0 + 7) * H2 + n]);
                *(uint4*)(out + o) = w;
            }
        } else if (t < 128) {
            const float* src = (set ? rW3 : W3) + (size_t)c * (H2 * H3);
            char* out = (char*)dstW3 + ((size_t)set * Cn + c) * 2048;
            const int o = t * 16;
            const int n = o >> 7;
            const int slot = (o >> 4) & 7;
            const int kk0 = (slot ^ (n & 7)) * 8;
            uint4 w;
            w.x = pack2(src[(kk0 + 0) * H3 + n], src[(kk0 + 1) * H3 + n]);
            w.y = pack2(src[(kk0 + 2) * H3 + n], src[(kk0 + 3) * H3 + n]);
            w.z = pack2(src[(kk0 + 4) * H3 + n], src[(kk0 + 5) * H3 + n]);
            w.w = pack2(src[(kk0 + 6) * H3 + n], src[(kk0 + 7) * H3 + n]);
            *(uint4*)(out + o) = w;
        }
    }
}

// ===================== Pass B: 128x256, wave 64x128, BK=32, ring-3, 1-barrier =====================
// LDS (72KB): A ring 3 x 8KB @ 0; B ring 3 x 16KB @ 24576.
// Post-loop reuse: x1 bf16 [128 rows][512B] @0 (64KB); then x2 bf16 [128][128B] @0.
// Swapped-operand MFMAs: mfma(W-frag, X-frag, acc) -> lane&15 = batch row,
// (lane>>4)*4+r = feature.
//
// Single-barrier ledger: iter j = {reads slot j%3 | stage slot (j+2)%3 | VMCNT6 | MFMA} BAR.

__device__ __forceinline__ void stageA(char* lds, const char* hb, int slot, int kt, int t) {
    const char* g = hb + (size_t)kt * 8192 + t * 16;
    char* l = lds + slot * 8192 + t * 16;
    load_lds16(g,        l);
    load_lds16(g + 4096, l + 4096);
}
__device__ __forceinline__ void stageB(char* lds, const char* w1b, int slot, int kt, int t) {
    const char* g = w1b + (size_t)kt * 16384 + t * 16;
    char* l = lds + 24576 + slot * 16384 + t * 16;
    load_lds16(g,         l);
    load_lds16(g + 4096,  l + 4096);
    load_lds16(g + 8192,  l + 8192);
    load_lds16(g + 12288, l + 12288);
}

__global__ __launch_bounds__(256, 2)
void scores_mfma_w128(const ushort* __restrict__ hbs, const ushort* __restrict__ W1ts,
                      const ushort* __restrict__ W2ts, const ushort* __restrict__ W3ts,
                      const float* __restrict__ b1, const float* __restrict__ rb1,
                      const float* __restrict__ b2, const float* __restrict__ rb2,
                      const float* __restrict__ b3, const float* __restrict__ rb3,
                      const float* __restrict__ W4, const float* __restrict__ rW4,
                      const float* __restrict__ b4, const float* __restrict__ rb4,
                      const float* __restrict__ W5, const float* __restrict__ rW5,
                      const float* __restrict__ b5, const float* __restrict__ rb5,
                      float* __restrict__ scores)
{
    __shared__ uint4 smv[73728 / 16];    // 72KB
    char* lds = (char*)smv;

    const int t = threadIdx.x;
    const int wid = t >> 6, lane = t & 63;
    const int lrow = lane & 15;
    const int lkg  = lane >> 4;          // 0..3
    const int lk   = lkg * 8;
    const int wr  = wid >> 1;            // 0..1 : rows wr*64
    const int wcn = wid & 1;             // 0..1 : cols wcn*128

    // bijective XCD swizzle, nwg = 5120
    const int cpx = 5120 >> 3;
    const int wg  = (blockIdx.x & 7) * cpx + (blockIdx.x >> 3);
    const int set = wg / 2560;
    const int rem = wg % 2560;
    const int c   = rem / 32;
    const int bt  = rem % 32;            // 128-row tile index

    const float* pb1 = set ? rb1 : b1;
    const float* pb2 = set ? rb2 : b2;
    const float* pb3 = set ? rb3 : b3;
    const float* pW4 = set ? rW4 : W4;  const float* pb4 = set ? rb4 : b4;
    const float* pW5 = set ? rW5 : W5;  const float* pb5 = set ? rb5 : b5;

    const char* hb  = (const char*)hbs + (size_t)bt * 196608;               // 24*8KB
    const char* w1b = (const char*)W1ts + (size_t)(set * Cn + c) * 393216;  // 24*16KB

    f32x4 acc[4][8];
    #pragma unroll
    for (int i = 0; i < 4; ++i)
        #pragma unroll
        for (int j = 0; j < 8; ++j)
            acc[i][j] = (f32x4){0.f, 0.f, 0.f, 0.f};

    // -------- prologue: tiles 0,1 (12 issues); wait tile 0 (leave tile 1's 6)
    stageA(lds, hb, 0, 0, t);  stageB(lds, w1b, 0, 0, t);
    stageA(lds, hb, 1, 1, t);  stageB(lds, w1b, 1, 1, t);
    VMCNT6();
    BAR();

    // -------- K loop: 24 iters of K=32, ONE barrier per iter
    #pragma unroll 3
    for (int j = 0; j < 24; ++j) {
        const int rs = j % 3;
        short8 breg[8], areg[4];
        {
            const char* bb = lds + 24576 + rs * 16384;
            const char* ab = lds + rs * 8192;
            #pragma unroll
            for (int nt = 0; nt < 8; ++nt) {
                const int col = wcn * 128 + nt * 16 + lrow;
                breg[nt] = *(const short8*)(bb + col * 64
                              + ((2 * lk) ^ (((col >> 1) & 3) << 4)));
            }
            #pragma unroll
            for (int mt = 0; mt < 4; ++mt) {
                const int row = wr * 64 + mt * 16 + lrow;
                areg[mt] = *(const short8*)(ab + row * 64
                              + ((2 * lk) ^ (((row >> 1) & 3) << 4)));
            }
        }
        {
            const int ws = (j + 2) % 3;
            int ka = j + 2; if (ka >= 24) ka -= 24;   // tail wrap: dead but uniform
            stageA(lds, hb, ws, ka, t);
            stageB(lds, w1b, ws, ka, t);
        }
        VMCNT6();
        __builtin_amdgcn_s_setprio(1);
        #pragma unroll
        for (int mt = 0; mt < 4; ++mt)
            #pragma unroll
            for (int nt = 0; nt < 8; ++nt)
                acc[mt][nt] = __builtin_amdgcn_mfma_f32_16x16x32_bf16(
                    breg[nt], areg[mt], acc[mt][nt], 0, 0, 0);
        __builtin_amdgcn_s_setprio(0);
        BAR();
    }
    VMCNT0();    // drain wrapped dead stages before LDS reuse
    BAR();

    // -------- epilogue 1: bias + relu -> x1 bf16 [128 rows][256 feat] swizzled
    {
        float4 bias1[8];
        #pragma unroll
        for (int nt = 0; nt < 8; ++nt)
            bias1[nt] = *(const float4*)&pb1[(size_t)c * H1 + wcn * 128 + nt * 16 + lkg * 4];
        #pragma unroll
        for (int mt = 0; mt < 4; ++mt) {
            const int row = wr * 64 + mt * 16 + lrow;
            const int swz = (row & 7) << 4;
            #pragma unroll
            for (int nt = 0; nt < 8; ++nt) {
                const float* bb = (const float*)&bias1[nt];
                uint2 w;
                w.x = pack2(fmaxf(acc[mt][nt][0] + bb[0], 0.f),
                            fmaxf(acc[mt][nt][1] + bb[1], 0.f));
                w.y = pack2(fmaxf(acc[mt][nt][2] + bb[2], 0.f),
                            fmaxf(acc[mt][nt][3] + bb[3], 0.f));
                const int off = row * 512 + ((wcn * 256 + nt * 32 + lkg * 8) ^ swz);
                *(uint2*)(lds + off) = w;
            }
        }
    }
    BAR();

    // -------- layer 2: M=128 N=64 K=256; per wave 32 rows
    f32x4 acc2[2][4];
    #pragma unroll
    for (int i = 0; i < 2; ++i)
        #pragma unroll
        for (int j = 0; j < 4; ++j)
            acc2[i][j] = (f32x4){0.f, 0.f, 0.f, 0.f};
    {
        const char* w2b = (const char*)W2ts + (size_t)(set * Cn + c) * 32768;
        #pragma unroll
        for (int ksz = 0; ksz < 8; ++ksz) {
            short8 b2r[4], a2[2];
            const int kk2 = (ksz & 1) * 32 + lk;
            #pragma unroll
            for (int nt = 0; nt < 4; ++nt) {
                const int col = nt * 16 + lrow;
                b2r[nt] = *(const short8*)(w2b + (ksz >> 1) * 8192
                             + ((col * 128 + 2 * kk2) ^ ((col & 7) << 4)));
            }
            const int k = ksz * 32 + lk;
            #pragma unroll
            for (int m2 = 0; m2 < 2; ++m2) {
                const int row = wid * 32 + m2 * 16 + lrow;
                a2[m2] = *(const short8*)(lds + ((row * 512 + 2 * k) ^ ((row & 7) << 4)));
            }
            #pragma unroll
            for (int m2 = 0; m2 < 2; ++m2)
                #pragma unroll
                for (int nt = 0; nt < 4; ++nt)
                    acc2[m2][nt] = __builtin_amdgcn_mfma_f32_16x16x32_bf16(
                        b2r[nt], a2[m2], acc2[m2][nt], 0, 0, 0);
        }
    }
    BAR();

    // -------- epilogue 2: bias + relu -> x2 bf16 [128 rows][64 feat] swizzled (16KB @0)
    {
        float4 bias2[4];
        #pragma unroll
        for (int nt = 0; nt < 4; ++nt)
            bias2[nt] = *(const float4*)&pb2[(size_t)c * H2 + nt * 16 + lkg * 4];
        #pragma unroll
        for (int m2 = 0; m2 < 2; ++m2) {
            const int row = wid * 32 + m2 * 16 + lrow;
            const int swz = (row & 7) << 4;
            #pragma unroll
            for (int nt = 0; nt < 4; ++nt) {
                const float* bb = (const float*)&bias2[nt];
                uint2 w;
                w.x = pack2(fmaxf(acc2[m2][nt][0] + bb[0], 0.f),
                            fmaxf(acc2[m2][nt][1] + bb[1], 0.f));
                w.y = pack2(fmaxf(acc2[m2][nt][2] + bb[2], 0.f),
                            fmaxf(acc2[m2][nt][3] + bb[3], 0.f));
                const int off = row * 128 + ((nt * 32 + lkg * 8) ^ swz);
                *(uint2*)(lds + off) = w;
            }
        }
    }
    BAR();

    // -------- layer 3 (MFMA) + layers 4-5 in-register
    {
        const char* w3t = (const char*)W3ts + (size_t)(set * Cn + c) * 2048;
        short8 w3f[2];
        #pragma unroll
        for (int ks = 0; ks < 2; ++ks)
            w3f[ks] = *(const short8*)(w3t + lrow * 128
                         + ((2 * (ks * 32 + lk)) ^ ((lrow & 7) << 4)));
        f32x4 acc3[2];
        #pragma unroll
        for (int m2 = 0; m2 < 2; ++m2) acc3[m2] = (f32x4){0.f, 0.f, 0.f, 0.f};
        #pragma unroll
        for (int m2 = 0; m2 < 2; ++m2) {
            const int row = wid * 32 + m2 * 16 + lrow;
            #pragma unroll
            for (int ks = 0; ks < 2; ++ks) {
                const short8 xf = *(const short8*)(lds + row * 128
                                     + ((2 * (ks * 32 + lk)) ^ ((row & 7) << 4)));
                acc3[m2] = __builtin_amdgcn_mfma_f32_16x16x32_bf16(
                    w3f[ks], xf, acc3[m2], 0, 0, 0);
            }
        }

        const float4 b3v = *(const float4*)&pb3[(size_t)c * H3 + lkg * 4];
        const float* w4c = pW4 + (size_t)c * (H3 * H4);
        float4 w4r[4];
        #pragma unroll
        for (int r = 0; r < 4; ++r)
            w4r[r] = *(const float4*)&w4c[(lkg * 4 + r) * H4];
        const float4 b4v = *(const float4*)&pb4[(size_t)c * H4];
        const float4 w5v = *(const float4*)&pW5[(size_t)c * H4];
        const float bb5 = pb5[c];

        #pragma unroll
        for (int m2 = 0; m2 < 2; ++m2) {
            float p4[4] = {0.f, 0.f, 0.f, 0.f};
            #pragma unroll
            for (int r = 0; r < 4; ++r) {
                const float x3 = fmaxf(acc3[m2][r] + ((const float*)&b3v)[r], 0.f);
                const float* wr4 = (const float*)&w4r[r];
                #pragma unroll
                for (int o = 0; o < 4; ++o)
                    p4[o] = fmaf(x3, wr4[o], p4[o]);
            }
            #pragma unroll
            for (int o = 0; o < 4; ++o) {
                p4[o] += __shfl_xor(p4[o], 16, 64);
                p4[o] += __shfl_xor(p4[o], 32, 64);
            }
            float x5 = bb5;
            #pragma unroll
            for (int o = 0; o < 4; ++o)
                x5 = fmaf(fmaxf(p4[o] + ((const float*)&b4v)[o], 0.f),
                          ((const float*)&w5v)[o], x5);
            const float sc = 1.f / (1.f + expf(-x5));
            if (lkg == 0)
                scores[((size_t)set * Bn + bt * 128 + wid * 32 + m2 * 16 + lrow) * Cn + c] = sc;
        }
    }
}

// ===================== loss kernels =====================
__device__ inline float bce_f(float p, float y) {
    p = fminf(fmaxf(p, 1e-8f), 1.0f - 1e-8f);
    return -(y * logf(p) + (1.f - y) * log1pf(-p));
}

__global__ __launch_bounds__(128)
void loss_kernel(const float* __restrict__ scores, const int* __restrict__ labels,
                 float* __restrict__ pair_sum, float* __restrict__ np_sum,
                 int* __restrict__ pair_cnt)
{
    __shared__ float ss[Cn], lt[Cn];
    __shared__ int lab[Cn];
    __shared__ float redf[128], redn[128];
    __shared__ int redi[128];

    const int b = blockIdx.x, t = threadIdx.x;
    float np_local = 0.f, ps_local = 0.f;
    int pc_local = 0;

    if (t < Cn) {
        const float s  = scores[(size_t)b * Cn + t];
        const float sr = scores[(size_t)Bn * Cn + (size_t)b * Cn + t];
        const int l = labels[(size_t)b * Cn + t];
        ss[t] = s; lab[t] = l;
        lt[t] = logf(s / (sr + 1e-8f) + 1e-8f);
        if (t >= 20) {
            const float y = (float)l;
            np_local = fmaxf(bce_f(s, y) - bce_f(sr, y) - 0.1f, 0.f);
        }
    }
    __syncthreads();
    if (t < Cn && lab[t] == 0) {
        const float sj = ss[t], ltj = lt[t];
        #pragma unroll
        for (int i = 0; i < 20; ++i) {
            if (lab[i] == 1 && sj >= ss[i]) {
                const float z = -(lt[i] - ltj);
                ps_local += fmaxf(z, 0.f) + log1pf(expf(-fabsf(z)));
                pc_local++;
            }
        }
    }
    redf[t] = ps_local; redn[t] = np_local; redi[t] = pc_local;
    __syncthreads();
    for (int s = 64; s > 0; s >>= 1) {
        if (t < s) { redf[t] += redf[t + s]; redn[t] += redn[t + s]; redi[t] += redi[t + s]; }
        __syncthreads();
    }
    if (t == 0) { pair_sum[b] = redf[0]; np_sum[b] = redn[0]; pair_cnt[b] = redi[0]; }
}

__global__ __launch_bounds__(1024)
void final_kernel(const float* __restrict__ pair_sum, const int* __restrict__ pair_cnt,
                  const float* __restrict__ np_sum, float* __restrict__ out)
{
    __shared__ float r1[1024], r2[1024];
    __shared__ int ri[1024];
    const int t = threadIdx.x;
    float s1 = 0.f, s2 = 0.f; int c1 = 0;
    for (int i = t; i < Bn; i += 1024) { s1 += pair_sum[i]; c1 += pair_cnt[i]; s2 += np_sum[i]; }
    r1[t] = s1; r2[t] = s2; ri[t] = c1;
    __syncthreads();
    for (int s = 512; s > 0; s >>= 1) {
        if (t < s) { r1[t] += r1[t + s]; r2[t] += r2[t + s]; ri[t] += ri[t + s]; }
        __syncthreads();
    }
    if (t == 0) {
        const int n = ri[0];
        out[0] = (n > 0) ? (r1[0] / (float)(n > 1 ? n : 1)) : 0.f;
        out[1] = r2[0] / (float)(Bn * 60);
    }
}

// ===================== launch =====================
static inline size_t alup(size_t x) { return (x + 4095) & ~(size_t)4095; }

extern "C" void kernel_launch(void* const* d_in, const int* in_sizes, int n_in,
                              void* d_out, int out_size, void* d_ws, size_t ws_size,
                              hipStream_t stream)
{
    const float* hidden = (const float*)d_in[0];
    const int*   labels = (const int*)d_in[1];
    const float* W1 = (const float*)d_in[2];   const float* b1 = (const float*)d_in[3];
    const float* W2 = (const float*)d_in[4];   const float* b2 = (const float*)d_in[5];
    const float* W3 = (const float*)d_in[6];   const float* b3 = (const float*)d_in[7];
    const float* W4 = (const float*)d_in[8];   const float* b4 = (const float*)d_in[9];
    const float* W5 = (const float*)d_in[10];  const float* b5 = (const float*)d_in[11];
    const float* rW1 = (const float*)d_in[12]; const float* rb1 = (const float*)d_in[13];
    const float* rW2 = (const float*)d_in[14]; const float* rb2 = (const float*)d_in[15];
    const float* rW3 = (const float*)d_in[16]; const float* rb3 = (const float*)d_in[17];
    const float* rW4 = (const float*)d_in[18]; const float* rb4 = (const float*)d_in[19];
    const float* rW5 = (const float*)d_in[20]; const float* rb5 = (const float*)d_in[21];

    char* ws = (char*)d_ws;
    const size_t off_scores = 0;
    const size_t sz_scores  = (size_t)2 * Bn * Cn * 4;
    const size_t off_pair   = alup(off_scores + sz_scores);
    const size_t sz_pair    = (size_t)3 * Bn * 4;
    const size_t off_hbs    = alup(off_pair + sz_pair);
    const size_t sz_hbs     = (size_t)Bn * Dn * 2;
    const size_t off_w1t    = alup(off_hbs + sz_hbs);
    const size_t sz_w1t     = (size_t)2 * Cn * 24 * 16384;
    const size_t off_w2t    = alup(off_w1t + sz_w1t);
    const size_t sz_w2t     = (size_t)2 * Cn * 4 * 8192;
    const size_t off_w3t    = alup(off_w2t + sz_w2t);

    float* scoresb  = (float*)(ws + off_scores);
    float* pair_sum = (float*)(ws + off_pair);
    float* np_sum   = pair_sum + Bn;
    int*   pair_cnt = (int*)(np_sum + Bn);
    float* out      = (float*)d_out;

    ushort* hbs  = (ushort*)(ws + off_hbs);
    ushort* W1ts = (ushort*)(ws + off_w1t);
    ushort* W2ts = (ushort*)(ws + off_w2t);
    ushort* W3ts = (ushort*)(ws + off_w3t);

    convert_all<<<5408, 256, 0, stream>>>(hidden, hbs, W1, rW1, W1ts,
                                          W2, rW2, W3, rW3, W2ts, W3ts);

    scores_mfma_w128<<<5120, 256, 0, stream>>>(hbs, W1ts, W2ts, W3ts,
        b1, rb1, b2, rb2, b3, rb3, W4, rW4, b4, rb4, W5, rW5, b5, rb5,
        scoresb);
    loss_kernel<<<Bn, 128, 0, stream>>>(scoresb, labels, pair_sum, np_sum, pair_cnt);
    final_kernel<<<1, 1024, 0, stream>>>(pair_sum, pair_cnt, np_sum, out);
}